// Round 11
// baseline (942.725 us; speedup 1.0000x reference)
//
#include <hip/hip_runtime.h>

#define NROWS 32768
#define DDIM  512
#define KCENT 8192

// out layout (floats): qout[16777216] loss[16777216] idx[32768] cbv[4194304] counts[8192]
#define O_LOSS 16777216
#define O_IDX  33554432
#define O_CBV  33587200
#define O_CNT  37781504

typedef float f32x4 __attribute__((ext_vector_type(4)));
typedef _Float16 f16x8 __attribute__((ext_vector_type(8)));

// ---- kernel 0: fp32 -> f16, 8-slot XOR pre-swizzle within each 128B K-chunk ----
// slot u of (row r, chunk dk) holds logical unit u^(r&7)
__global__ __launch_bounds__(256) void vq_cvt_swz8(
    const float* __restrict__ src, char* __restrict__ dst)
{
    const int gid = blockIdx.x * 256 + threadIdx.x;   // one 16B f16 unit (8 floats)
    const int r = gid >> 6, w = gid & 63, dk = w >> 3, u = w & 7;
    const float4* p = (const float4*)(src + (size_t)r * DDIM + (dk*8 + (u ^ (r & 7))) * 8);
    float4 a = p[0], b = p[1];
    f16x8 h;
    h[0]=(_Float16)a.x; h[1]=(_Float16)a.y; h[2]=(_Float16)a.z; h[3]=(_Float16)a.w;
    h[4]=(_Float16)b.x; h[5]=(_Float16)b.y; h[6]=(_Float16)b.z; h[7]=(_Float16)b.w;
    *(f16x8*)(dst + (size_t)gid * 16) = h;
}

// ---- kernel 1: centroid squared norms (fp64 accumulate) + counts=1 ----
__global__ __launch_bounds__(256) void vq_cnorm_kernel(
    const float* __restrict__ CB, float* __restrict__ cnorm, float* __restrict__ counts)
{
    const int wid  = threadIdx.x >> 6;
    const int lane = threadIdx.x & 63;
    const int cid  = blockIdx.x * 4 + wid;
    const float4* p = (const float4*)(CB + (size_t)cid * DDIM + lane * 8);
    float4 a = p[0], b = p[1];
    double s = (double)a.x*a.x + (double)a.y*a.y + (double)a.z*a.z + (double)a.w*a.w
             + (double)b.x*b.x + (double)b.y*b.y + (double)b.z*b.z + (double)b.w*b.w;
    #pragma unroll
    for (int off = 32; off > 0; off >>= 1) s += __shfl_down(s, off);
    if (lane == 0) { cnorm[cid] = (float)s; counts[cid] = 1.0f; }
}

__device__ __forceinline__ void t2_update(float s, int c,
                                          float& v1, int& i1, float& v2, int& i2)
{
    if (s < v1)      { v2 = v1; i2 = i1; v1 = s; i1 = c; }
    else if (s < v2) { v2 = s;  i2 = c; }
}

__device__ __forceinline__ void t2_merge(float b1, int bi1, float b2, int bi2,
                                         float& a1, int& ai1, float& a2, int& ai2)
{
    if (b1 < a1 || (b1 == a1 && bi1 < ai1)) {
        float o1 = a1; int oi1 = ai1;
        a1 = b1; ai1 = bi1;
        if (b2 < o1 || (b2 == o1 && bi2 < oi1)) { a2 = b2; ai2 = bi2; }
        else                                    { a2 = o1; ai2 = oi1; }
    } else {
        if (b1 < a2 || (b1 == a2 && bi1 < ai2)) { a2 = b1; ai2 = bi1; }
    }
}

__device__ __forceinline__ void gl16(const char* g, const char* l)
{
    __builtin_amdgcn_global_load_lds(
        (const __attribute__((address_space(1))) void*)g,
        (__attribute__((address_space(3))) void*)l, 16, 0, 0);
}

// ---- kernel 2: per-CU sweep GEMM: 128 rows x ALL 8192 cols per block ----
// 512 thr, 8 waves = 4 rg (32 rows, m=2) x 2 cg (64 cols, n=4).
// A resident in registers (Areg[2][16], loaded once); B LDS-dbuf 2x32KB,
// counted vmcnt; 256 phases of 4 ksteps; per-tile reg top-2; one final merge.
__global__ __launch_bounds__(512, 2) void vq_gemm_kernel(
    const char* __restrict__ Xf, const char* __restrict__ Cf,
    const float* __restrict__ cnorm, int* __restrict__ pmini2)
{
    __shared__ __align__(16) char lds[65536];

    const int rb   = blockIdx.x;     // row-tile 0..255 (rows rb*128 ..)
    const int t    = threadIdx.x;
    const int lane = t & 63;
    const int wid  = t >> 6;
    const int rg   = wid & 3;        // 4 row-groups of 32
    const int cg   = wid >> 2;       // 2 col-groups of 64
    const int l15  = lane & 15;
    const int lg   = lane >> 4;

    // ---- prologue: load A fragments into registers via two 64KB LDS chunks ----
    f16x8 Areg[2][16];
    #pragma unroll
    for (int c = 0; c < 2; ++c) {
        __syncthreads();
        #pragma unroll
        for (int i = 0; i < 8; ++i) {
            const int g = i*512 + t;     // row-local g>>6, unit g&63 (1 row per wave-instr)
            gl16(Xf + ((size_t)(rb*128 + c*64 + (g >> 6)))*1024 + (g & 63)*16,
                 &lds[g*16]);
        }
        __syncthreads();                 // drains vmcnt -> chunk visible
        if ((rg >> 1) == c) {
            #pragma unroll
            for (int m = 0; m < 2; ++m) {
                const int lr = (rg & 1)*32 + m*16 + l15;   // local row in chunk
                #pragma unroll
                for (int ks = 0; ks < 16; ++ks) {
                    const int ku = ks*4 + lg;
                    Areg[m][ks] = *(const f16x8*)(
                        &lds[lr*1024 + (ku >> 3)*128 + (((ku & 7) ^ (lr & 7)) * 16)]);
                }
            }
        }
    }
    __syncthreads();   // all A reads done before B staging overwrites LDS

    // B stage: phase P covers col-tile P>>2, K-bytes (P&3)*256..+256 per col.
    // 2048 units of 16B; thread stages 4 (raw copy, layout mirrors global swz8).
    #define STAGE_B(P, buf) {                                                   \
        const int ctP_ = (P) >> 2, sp_ = (P) & 3;                               \
        _Pragma("unroll")                                                       \
        for (int i = 0; i < 4; ++i) {                                           \
            const int g = i*512 + t;                                            \
            gl16(Cf + ((size_t)(ctP_*128 + (g >> 4)))*1024 + sp_*256 + (g & 15)*16, \
                 &lds[(buf)*32768 + g*16]);                                     \
        } }

    f32x4 acc[2][4];
    float rv1[2][4], rv2[2][4];
    int   ri1[2][4], ri2[2][4];
    #pragma unroll
    for (int m = 0; m < 2; ++m)
        #pragma unroll
        for (int n = 0; n < 4; ++n) {
            f32x4 z = {0.f,0.f,0.f,0.f};
            acc[m][n] = z;
            rv1[m][n] = 3.4e38f; rv2[m][n] = 3.4e38f;
            ri1[m][n] = 0x7fffffff; ri2[m][n] = 0x7fffffff;
        }

    STAGE_B(0, 0);
    asm volatile("s_waitcnt vmcnt(0)\n\ts_barrier" ::: "memory");

    const int rB0 = cg*64 +  0 + l15;
    const int rB1 = cg*64 + 16 + l15;
    const int rB2 = cg*64 + 32 + l15;
    const int rB3 = cg*64 + 48 + l15;

    for (int ct = 0; ct < 64; ++ct) {
        #pragma unroll
        for (int ph = 0; ph < 4; ++ph) {          // MUST unroll: Areg index static
            const int P = ct*4 + ph;
            if (P + 1 < 256) {
                STAGE_B(P + 1, (P + 1) & 1);
                asm volatile("s_waitcnt vmcnt(4)\n\ts_barrier" ::: "memory");
            } else {
                asm volatile("s_waitcnt vmcnt(0)\n\ts_barrier" ::: "memory");
            }
            const char* bb = &lds[(P & 1)*32768];
            #pragma unroll
            for (int ksl = 0; ksl < 4; ++ksl) {
                const int ks  = ph*4 + ksl;       // static
                const int kuF = ksl*4 + lg;       // unit within phase (0..15)
                const int co  = (kuF >> 3)*128;
                const int sl  = kuF & 7;
                f16x8 B0 = *(const f16x8*)(bb + rB0*256 + co + ((sl ^ (rB0 & 7)) * 16));
                f16x8 B1 = *(const f16x8*)(bb + rB1*256 + co + ((sl ^ (rB1 & 7)) * 16));
                f16x8 B2 = *(const f16x8*)(bb + rB2*256 + co + ((sl ^ (rB2 & 7)) * 16));
                f16x8 B3 = *(const f16x8*)(bb + rB3*256 + co + ((sl ^ (rB3 & 7)) * 16));
                #pragma unroll
                for (int m = 0; m < 2; ++m) {
                    acc[m][0] = __builtin_amdgcn_mfma_f32_16x16x32_f16(Areg[m][ks], B0, acc[m][0], 0, 0, 0);
                    acc[m][1] = __builtin_amdgcn_mfma_f32_16x16x32_f16(Areg[m][ks], B1, acc[m][1], 0, 0, 0);
                    acc[m][2] = __builtin_amdgcn_mfma_f32_16x16x32_f16(Areg[m][ks], B2, acc[m][2], 0, 0, 0);
                    acc[m][3] = __builtin_amdgcn_mfma_f32_16x16x32_f16(Areg[m][ks], B3, acc[m][3], 0, 0, 0);
                }
            }
            asm volatile("s_barrier" ::: "memory");   // reads done before buf restage
        }
        // per-tile epilogue: score = ||c||^2 - 2*dot ; running top-2 (cols ascending)
        const int colb = ct*128 + cg*64;
        #pragma unroll
        for (int n = 0; n < 4; ++n) {
            const int col = colb + n*16 + l15;
            const float cn = cnorm[col];
            #pragma unroll
            for (int m = 0; m < 2; ++m) {
                #pragma unroll
                for (int j = 0; j < 4; ++j) {
                    const float s = fmaf(-2.0f, acc[m][n][j], cn);
                    t2_update(s, col, rv1[m][j], ri1[m][j], rv2[m][j], ri2[m][j]);
                }
                f32x4 z = {0.f,0.f,0.f,0.f};
                acc[m][n] = z;
            }
        }
    }
    #undef STAGE_B

    // cross-lane top-2 merge over the 16 l15 lanes (same rows, different cols)
    #pragma unroll
    for (int m = 0; m < 2; ++m)
        #pragma unroll
        for (int j = 0; j < 4; ++j) {
            #pragma unroll
            for (int off = 1; off <= 8; off <<= 1) {
                float b1 = __shfl_xor(rv1[m][j], off);
                float b2 = __shfl_xor(rv2[m][j], off);
                int  bi1 = __shfl_xor(ri1[m][j], off);
                int  bi2 = __shfl_xor(ri2[m][j], off);
                t2_merge(b1, bi1, b2, bi2, rv1[m][j], ri1[m][j], rv2[m][j], ri2[m][j]);
            }
        }

    // cross-wave merge over the 2 cg groups via LDS; write global top-2 per row
    float4* red = (float4*)&lds[0];    // [128 rows][2 cg]
    __syncthreads();
    if (l15 == 0) {
        #pragma unroll
        for (int m = 0; m < 2; ++m)
            #pragma unroll
            for (int j = 0; j < 4; ++j) {
                const int rl = rg*32 + m*16 + lg*4 + j;
                float4 w;
                w.x = rv1[m][j]; w.y = __int_as_float(ri1[m][j]);
                w.z = rv2[m][j]; w.w = __int_as_float(ri2[m][j]);
                red[rl*2 + cg] = w;
            }
    }
    __syncthreads();
    if (t < 128) {
        float4 e0 = red[t*2 + 0], e1 = red[t*2 + 1];
        float v1 = e0.x, v2 = e0.z;
        int   i1 = __float_as_int(e0.y), i2 = __float_as_int(e0.w);
        t2_merge(e1.x, __float_as_int(e1.y), e1.z, __float_as_int(e1.w), v1, i1, v2, i2);
        pmini2[(rb*128 + t)*2 + 0] = i1;
        pmini2[(rb*128 + t)*2 + 1] = i2;
    }
}

// ---- kernel 3: exact fp64 resolve of the 2 candidates + write all outputs ----
__global__ __launch_bounds__(256) void vq_resolve_out(
    const float* __restrict__ X, const float* __restrict__ CB,
    const int* __restrict__ pmini2, float* __restrict__ out)
{
    const int wid  = threadIdx.x >> 6;
    const int lane = threadIdx.x & 63;
    const int row  = blockIdx.x * 4 + wid;
    const int i0 = pmini2[row*2 + 0], i1 = pmini2[row*2 + 1];

    const float4* xp = (const float4*)(X + (size_t)row * DDIM + lane * 8);
    float4 xa = xp[0], xb = xp[1];
    const float4* p0 = (const float4*)(CB + (size_t)i0 * DDIM + lane * 8);
    float4 c0a = p0[0], c0b = p0[1];
    const float4* p1 = (const float4*)(CB + (size_t)i1 * DDIM + lane * 8);
    float4 c1a = p1[0], c1b = p1[1];

    double d0 = 0.0, d1 = 0.0, e;
    e = (double)xa.x - c0a.x; d0 += e*e;  e = (double)xa.y - c0a.y; d0 += e*e;
    e = (double)xa.z - c0a.z; d0 += e*e;  e = (double)xa.w - c0a.w; d0 += e*e;
    e = (double)xb.x - c0b.x; d0 += e*e;  e = (double)xb.y - c0b.y; d0 += e*e;
    e = (double)xb.z - c0b.z; d0 += e*e;  e = (double)xb.w - c0b.w; d0 += e*e;
    e = (double)xa.x - c1a.x; d1 += e*e;  e = (double)xa.y - c1a.y; d1 += e*e;
    e = (double)xa.z - c1a.z; d1 += e*e;  e = (double)xa.w - c1a.w; d1 += e*e;
    e = (double)xb.x - c1b.x; d1 += e*e;  e = (double)xb.y - c1b.y; d1 += e*e;
    e = (double)xb.z - c1b.z; d1 += e*e;  e = (double)xb.w - c1b.w; d1 += e*e;
    #pragma unroll
    for (int off = 1; off < 64; off <<= 1) {
        d0 += __shfl_xor(d0, off);
        d1 += __shfl_xor(d1, off);
    }

    const bool w1 = (d1 < d0) || (d1 == d0 && i1 < i0);
    const int idxw = w1 ? i1 : i0;
    float4 qa, qb;
    qa.x = w1 ? c1a.x : c0a.x;  qa.y = w1 ? c1a.y : c0a.y;
    qa.z = w1 ? c1a.z : c0a.z;  qa.w = w1 ? c1a.w : c0a.w;
    qb.x = w1 ? c1b.x : c0b.x;  qb.y = w1 ? c1b.y : c0b.y;
    qb.z = w1 ? c1b.z : c0b.z;  qb.w = w1 ? c1b.w : c0b.w;

    float4 qoa, loa, qob, lob;
    float d, s;
    d = qa.x - xa.x; qoa.x = xa.x + d; s = d*d; loa.x = s + 0.25f*s;
    d = qa.y - xa.y; qoa.y = xa.y + d; s = d*d; loa.y = s + 0.25f*s;
    d = qa.z - xa.z; qoa.z = xa.z + d; s = d*d; loa.z = s + 0.25f*s;
    d = qa.w - xa.w; qoa.w = xa.w + d; s = d*d; loa.w = s + 0.25f*s;
    d = qb.x - xb.x; qob.x = xb.x + d; s = d*d; lob.x = s + 0.25f*s;
    d = qb.y - xb.y; qob.y = xb.y + d; s = d*d; lob.y = s + 0.25f*s;
    d = qb.z - xb.z; qob.z = xb.z + d; s = d*d; lob.z = s + 0.25f*s;
    d = qb.w - xb.w; qob.w = xb.w + d; s = d*d; lob.w = s + 0.25f*s;

    ((float4*)out)[(size_t)row*128 + lane*2 + 0] = qoa;
    ((float4*)out)[(size_t)row*128 + lane*2 + 1] = qob;
    ((float4*)(out + O_LOSS))[(size_t)row*128 + lane*2 + 0] = loa;
    ((float4*)(out + O_LOSS))[(size_t)row*128 + lane*2 + 1] = lob;
    if (lane == 0) out[O_IDX + row] = (float)idxw;
}

extern "C" void kernel_launch(void* const* d_in, const int* in_sizes, int n_in,
                              void* d_out, int out_size, void* d_ws, size_t ws_size,
                              hipStream_t stream)
{
    const float* X  = (const float*)d_in[0];
    const float* CB = (const float*)d_in[1];
    float* out = (float*)d_out;

    // big f16 scratch parked in out regions (all rewritten by the final kernels)
    char* XsB  = (char*)out;              // 32 MB swz8 f16 X   (qout front half)
    char* CBsB = (char*)(out + O_LOSS);   //  8 MB swz8 f16 CB  (loss region)

    float* cnorm  = (float*)d_ws;             // 8192 floats
    int*   pmini2 = (int*)(cnorm + KCENT);    // 2*32768 ints

    vq_cvt_swz8<<<(NROWS*64)/256, 256, 0, stream>>>(X, XsB);
    vq_cvt_swz8<<<(KCENT*64)/256, 256, 0, stream>>>(CB, CBsB);
    vq_cnorm_kernel<<<KCENT/4, 256, 0, stream>>>(CB, cnorm, out + O_CNT);
    vq_gemm_kernel<<<NROWS/128, 512, 0, stream>>>(XsB, CBsB, cnorm, pmini2);
    vq_resolve_out<<<NROWS/4, 256, 0, stream>>>(X, CB, pmini2, out);
    hipMemcpyAsync(out + O_CBV, CB, (size_t)KCENT * DDIM * sizeof(float),
                   hipMemcpyDeviceToDevice, stream);
}